// Round 13
// baseline (297.290 us; speedup 1.0000x reference)
//
#include <hip/hip_runtime.h>
#include <hip/hip_fp16.h>
#include <math.h>

typedef __attribute__((ext_vector_type(8))) short bf16x8;
typedef __attribute__((ext_vector_type(4))) float f32x4;

static __device__ __forceinline__ unsigned short f2bf(float x) {
    unsigned u = __float_as_uint(x);
    unsigned r = (u + 0x7FFF + ((u >> 16) & 1)) >> 16;
    return (unsigned short)r;
}
static __device__ __forceinline__ float bf2f(unsigned short h) {
    return __uint_as_float(((unsigned)h) << 16);
}
static __device__ __forceinline__ void addh8(float a[8], uint4 v) {
    float2 f;
    f = __half22float2(*(const __half2*)&v.x); a[0] += f.x; a[1] += f.y;
    f = __half22float2(*(const __half2*)&v.y); a[2] += f.x; a[3] += f.y;
    f = __half22float2(*(const __half2*)&v.z); a[4] += f.x; a[5] += f.y;
    f = __half22float2(*(const __half2*)&v.w); a[6] += f.x; a[7] += f.y;
}
// async global->LDS 16B copy: LDS dest = wave-uniform base + lane*16
static __device__ __forceinline__ void gll16(const unsigned short* g, unsigned short* l) {
    __builtin_amdgcn_global_load_lds(
        (const __attribute__((address_space(1))) unsigned int*)(const void*)g,
        (__attribute__((address_space(3))) unsigned int*)(void*)l, 16, 0, 0);
}

// ---------------- CSR build with 8-way replicated degree counters ----------------
// Edge e counts into replica e&7 -> no intra-wave same-address collisions, 8x less
// per-address contention on the atomic.

__global__ __launch_bounds__(256) void count_deg_kernel(const int* __restrict__ dst, int E, int n,
                                                        int* __restrict__ degR,
                                                        int* __restrict__ epos) {
    int e = blockIdx.x * 256 + threadIdx.x;
    if (e < E) epos[e] = atomicAdd(&degR[(e & 7) * n + dst[e]], 1);
}

__global__ __launch_bounds__(256) void scan_partial_kernel(const int* __restrict__ degR, int n,
                                                           int* __restrict__ partials) {
    int idx = blockIdx.x * 1024 + threadIdx.x * 4;
    int s = 0;
#pragma unroll
    for (int r = 0; r < 8; ++r) {
        const int* d = degR + (size_t)r * n;
        int4 v = make_int4(0, 0, 0, 0);
        if (idx + 3 < n) v = *(const int4*)(d + idx);
        else {
            if (idx < n) v.x = d[idx];
            if (idx + 1 < n) v.y = d[idx + 1];
            if (idx + 2 < n) v.z = d[idx + 2];
        }
        s += v.x + v.y + v.z + v.w;
    }
    for (int off = 1; off < 64; off <<= 1) s += __shfl_xor(s, off);
    __shared__ int sm[4];
    int wave = threadIdx.x >> 6;
    if ((threadIdx.x & 63) == 0) sm[wave] = s;
    __syncthreads();
    if (threadIdx.x == 0) partials[blockIdx.x] = sm[0] + sm[1] + sm[2] + sm[3];
}

__global__ __launch_bounds__(64) void scan_offsets_kernel(const int* __restrict__ partials, int nb,
                                                          int* __restrict__ poff,
                                                          int* __restrict__ rowptr, int n) {
    int t = threadIdx.x;
    int v = (t < nb) ? partials[t] : 0;
    int s = v;
    for (int off = 1; off < 64; off <<= 1) {
        int u = __shfl_up(s, off);
        if (t >= off) s += u;
    }
    poff[t] = s - v;
    if (t == 63) rowptr[n] = s;
}

__global__ __launch_bounds__(256) void scan_final_kernel(const int* __restrict__ degR, int n,
                                                         const int* __restrict__ poff,
                                                         int* __restrict__ rowptr) {
    int idx = blockIdx.x * 1024 + threadIdx.x * 4;
    int4 tv = make_int4(0, 0, 0, 0);
#pragma unroll
    for (int r = 0; r < 8; ++r) {
        const int* d = degR + (size_t)r * n;
        int4 v = make_int4(0, 0, 0, 0);
        if (idx + 3 < n) v = *(const int4*)(d + idx);
        else {
            if (idx < n) v.x = d[idx];
            if (idx + 1 < n) v.y = d[idx + 1];
            if (idx + 2 < n) v.z = d[idx + 2];
        }
        tv.x += v.x; tv.y += v.y; tv.z += v.z; tv.w += v.w;
    }
    int tsum = tv.x + tv.y + tv.z + tv.w;
    int lane = threadIdx.x & 63, wave = threadIdx.x >> 6;
    int s = tsum;
    for (int off = 1; off < 64; off <<= 1) {
        int u = __shfl_up(s, off);
        if (lane >= off) s += u;
    }
    __shared__ int wsum[4];
    if (lane == 63) wsum[wave] = s;
    __syncthreads();
    int base = poff[blockIdx.x];
    for (int w = 0; w < wave; ++w) base += wsum[w];
    int e0 = base + s - tsum;
    int4 o;
    o.x = e0; o.y = e0 + tv.x; o.z = o.y + tv.y; o.w = o.z + tv.z;
    if (idx + 3 < n) *(int4*)(rowptr + idx) = o;
    else {
        if (idx < n) rowptr[idx] = o.x;
        if (idx + 1 < n) rowptr[idx + 1] = o.y;
        if (idx + 2 < n) rowptr[idx + 2] = o.z;
    }
}

// per-node absolute base for each replica: repOff[r][d] = rowptr[d] + sum_{r'<r} degR[r'][d]
__global__ __launch_bounds__(256) void repsum_kernel(const int* __restrict__ degR,
                                                     const int* __restrict__ rowptr,
                                                     int* __restrict__ repOff, int n) {
    int d = blockIdx.x * 256 + threadIdx.x;
    if (d >= n) return;
    int base = rowptr[d];
#pragma unroll
    for (int r = 0; r < 8; ++r) {
        repOff[(size_t)r * n + d] = base;
        base += degR[(size_t)r * n + d];
    }
}

// ---------------- fused prep: scatter | dinv+prescale | W convert (block-range dispatch) --------

__global__ __launch_bounds__(256) void prep_kernel(
    // scatter part
    const int* __restrict__ src, const int* __restrict__ dst, const int* __restrict__ epos, int E,
    int n, const int* __restrict__ repOff, int* __restrict__ csrsrc, int scatterBlocks,
    // prescale part
    const float* __restrict__ x, const int* __restrict__ rowptr, float* __restrict__ dinv,
    __half2* __restrict__ xs16, int prescaleBlocks,
    // wconvert part
    const float* __restrict__ W1, const float* __restrict__ W2,
    unsigned short* __restrict__ w1h, unsigned short* __restrict__ w1l,
    unsigned short* __restrict__ w2h, unsigned short* __restrict__ w2l) {
    int b = blockIdx.x;
    if (b < scatterBlocks) {
        int e = b * 256 + threadIdx.x;
        if (e < E) csrsrc[repOff[(size_t)(e & 7) * n + dst[e]] + epos[e]] = src[e];
    } else if (b < scatterBlocks + prescaleBlocks) {
        int node = (b - scatterBlocks) * 4 + (threadIdx.x >> 6);
        int lane = threadIdx.x & 63;
        if (node >= n) return;
        float di = rsqrtf((float)(rowptr[node + 1] - rowptr[node] + 1));
        if (lane == 0) dinv[node] = di;
        float2 v = *(const float2*)(x + (size_t)node * 128 + (lane << 1));
        xs16[(size_t)node * 64 + lane] = __floats2half2_rn(di * v.x, di * v.y);
    } else {
        int i = (b - scatterBlocks - prescaleBlocks) * 256 + threadIdx.x;
        if (i < 128 * 128) {
            int nn = i >> 7, k = i & 127;
            float v = W1[k * 128 + nn];
            unsigned short h = f2bf(v);
            int kp = (k & 64) + ((((k >> 3) & 7) ^ (nn & 7)) << 3) + (k & 7);
            w1h[nn * 128 + kp] = h;
            w1l[nn * 128 + kp] = f2bf(v - bf2f(h));
        } else if (i < 128 * 128 + 256 * 128) {
            int j = i - 128 * 128;
            int nn = j >> 7, k = j & 127;
            float v = W2[k * 256 + nn];
            unsigned short h = f2bf(v);
            int kp = (k & 64) + ((((k >> 3) & 7) ^ (nn & 7)) << 3) + (k & 7);
            w2h[nn * 128 + kp] = h;
            w2l[nn * 128 + kp] = f2bf(v - bf2f(h));
        }
    }
}

// ---------------- aggregation: fp16 gather (unroll 4), fp32 accum, pre-swizzled bf16 out ---------

__global__ __launch_bounds__(256) void aggregate_kernel(const unsigned short* __restrict__ X16,
                                                        const float* __restrict__ dinv,
                                                        const int* __restrict__ rowptr,
                                                        const int* __restrict__ csrsrc,
                                                        unsigned short* __restrict__ outH,
                                                        unsigned short* __restrict__ outL, int n) {
    int node = blockIdx.x * 16 + (threadIdx.x >> 4);
    int sl = threadIdx.x & 15;
    if (node >= n) return;
    const uint4* Xv = (const uint4*)X16;
    float acc[8] = {0.f, 0.f, 0.f, 0.f, 0.f, 0.f, 0.f, 0.f};
    addh8(acc, Xv[(size_t)node * 16 + sl]);
    int e0 = rowptr[node];
    int e1 = rowptr[node + 1];
    int e = e0;
    for (; e + 4 <= e1; e += 4) {
        int s0 = csrsrc[e], s1 = csrsrc[e + 1], s2 = csrsrc[e + 2], s3 = csrsrc[e + 3];
        uint4 v0 = Xv[(size_t)s0 * 16 + sl];
        uint4 v1 = Xv[(size_t)s1 * 16 + sl];
        uint4 v2 = Xv[(size_t)s2 * 16 + sl];
        uint4 v3 = Xv[(size_t)s3 * 16 + sl];
        addh8(acc, v0); addh8(acc, v1); addh8(acc, v2); addh8(acc, v3);
    }
    for (; e < e1; ++e) {
        uint4 v = Xv[(size_t)csrsrc[e] * 16 + sl];
        addh8(acc, v);
    }
    float di = dinv[node];
    unsigned short h[8], l[8];
#pragma unroll
    for (int j = 0; j < 8; ++j) {
        float f = di * acc[j];
        h[j] = f2bf(f);
        l[j] = f2bf(f - bf2f(h[j]));
    }
    uint4 hv, lv;
    hv.x = (unsigned)h[0] | ((unsigned)h[1] << 16);
    hv.y = (unsigned)h[2] | ((unsigned)h[3] << 16);
    hv.z = (unsigned)h[4] | ((unsigned)h[5] << 16);
    hv.w = (unsigned)h[6] | ((unsigned)h[7] << 16);
    lv.x = (unsigned)l[0] | ((unsigned)l[1] << 16);
    lv.y = (unsigned)l[2] | ((unsigned)l[3] << 16);
    lv.z = (unsigned)l[4] | ((unsigned)l[5] << 16);
    lv.w = (unsigned)l[6] | ((unsigned)l[7] << 16);
    int pos = ((sl & 8) | ((sl & 7) ^ (node & 7))) * 8;   // pre-swizzled granule slot
    *(uint4*)(outH + (size_t)node * 128 + pos) = hv;
    *(uint4*)(outL + (size_t)node * 128 + pos) = lv;
}

// ---------------- split-bf16 MFMA GEMM (BK=64 + global_load_lds, pre-swizzled global) ------------

template <int N, bool SCALE_DINV, bool DO_LOGITS, bool OUT_F16>
__global__ __launch_bounds__(256, 2) void gemm_mfma(const unsigned short* __restrict__ Ah,
                                                    const unsigned short* __restrict__ Al,
                                                    const unsigned short* __restrict__ Bth,
                                                    const unsigned short* __restrict__ Btl,
                                                    const float* __restrict__ bias,
                                                    void* __restrict__ Cout, int M,
                                                    const float* __restrict__ dinv,
                                                    const float* __restrict__ Wa,
                                                    float* __restrict__ logits) {
    __shared__ unsigned short AsH[128 * 64];
    __shared__ unsigned short AsL[128 * 64];
    __shared__ unsigned short BsH[128 * 64];
    __shared__ unsigned short BsL[128 * 64];

    const int t = threadIdx.x;
    const int lane = t & 63;
    const int wave = t >> 6;
    const int wrow = wave >> 1;
    const int wcol = wave & 1;
    const int lq = lane >> 4;
    const int lm = lane & 15;
    const int row0 = blockIdx.x * 128;
    const int col0 = blockIdx.y * 128;

    const int lr = lane >> 3;        // row within 8-row segment
    const int p8 = (lane & 7) * 8;   // granule offset in shorts (swizzle lives in global layout)

    f32x4 acc[4][4] = {};
    float lacc[4][4] = {};

    for (int kc = 0; kc < 2; ++kc) {
        __syncthreads();
#pragma unroll
        for (int j = 0; j < 4; ++j) {
            int seg = wave * 4 + j;                 // 0..15 (8 rows each)
            int r = seg * 8 + lr;
            size_t goA = (size_t)(row0 + r) * 128 + kc * 64 + p8;
            size_t goB = (size_t)(col0 + r) * 128 + kc * 64 + p8;
            gll16(Ah + goA, AsH + seg * 512);
            gll16(Al + goA, AsL + seg * 512);
            gll16(Bth + goB, BsH + seg * 512);
            gll16(Btl + goB, BsL + seg * 512);
        }
        __syncthreads();

#pragma unroll
        for (int ks = 0; ks < 2; ++ks) {
            bf16x8 ah[4], al[4], bh[4], bl[4];
            int gbase = ks * 4 + lq;
#pragma unroll
            for (int rt = 0; rt < 4; ++rt) {
                int ra = wrow * 64 + rt * 16 + lm;
                int off = ra * 64 + (gbase ^ (ra & 7)) * 8;
                ah[rt] = *(const bf16x8*)(AsH + off);
                al[rt] = *(const bf16x8*)(AsL + off);
            }
#pragma unroll
            for (int ct = 0; ct < 4; ++ct) {
                int nb = wcol * 64 + ct * 16 + lm;
                int off = nb * 64 + (gbase ^ (nb & 7)) * 8;
                bh[ct] = *(const bf16x8*)(BsH + off);
                bl[ct] = *(const bf16x8*)(BsL + off);
            }
#pragma unroll
            for (int rt = 0; rt < 4; ++rt)
#pragma unroll
                for (int ct = 0; ct < 4; ++ct) {
                    acc[rt][ct] = __builtin_amdgcn_mfma_f32_16x16x32_bf16(ah[rt], bh[ct], acc[rt][ct], 0, 0, 0);
                    acc[rt][ct] = __builtin_amdgcn_mfma_f32_16x16x32_bf16(al[rt], bh[ct], acc[rt][ct], 0, 0, 0);
                    acc[rt][ct] = __builtin_amdgcn_mfma_f32_16x16x32_bf16(ah[rt], bl[ct], acc[rt][ct], 0, 0, 0);
                }
        }
    }

    // epilogue: C/D frag layout col = lm, row = lq*4 + reg
#pragma unroll
    for (int ct = 0; ct < 4; ++ct) {
        int col = col0 + wcol * 64 + ct * 16 + lm;
        float bc = bias[col];
        float wac = DO_LOGITS ? Wa[col] : 0.f;
#pragma unroll
        for (int rt = 0; rt < 4; ++rt) {
            int rowb = row0 + wrow * 64 + rt * 16 + lq * 4;
#pragma unroll
            for (int reg = 0; reg < 4; ++reg) {
                int gr = rowb + reg;
                if (gr < M) {
                    float o = fmaxf(acc[rt][ct][reg] + bc, 0.f);
                    if (SCALE_DINV) o *= dinv[gr];
                    if (OUT_F16) ((__half*)Cout)[(size_t)gr * N + col] = __float2half(o);
                    else ((float*)Cout)[(size_t)gr * N + col] = o;
                    if (DO_LOGITS) lacc[rt][reg] += o * wac;
                }
            }
        }
    }

    if (DO_LOGITS) {
#pragma unroll
        for (int rt = 0; rt < 4; ++rt)
#pragma unroll
            for (int reg = 0; reg < 4; ++reg) {
                float s = lacc[rt][reg];
                s += __shfl_xor(s, 1);
                s += __shfl_xor(s, 2);
                s += __shfl_xor(s, 4);
                s += __shfl_xor(s, 8);
                int gr = row0 + wrow * 64 + rt * 16 + lq * 4 + reg;
                if (lm == 0 && gr < M) atomicAdd(&logits[gr], s);
            }
    }
}

// ---------------- attention pooling (3 kernels) ----------------

__global__ __launch_bounds__(256) void maxsum_kernel(const float* __restrict__ logits, int n,
                                                     float2* __restrict__ part) {
    float m = -INFINITY, s = 0.f;
    for (int i = blockIdx.x * 256 + threadIdx.x; i < n; i += gridDim.x * 256) {
        float v = logits[i];
        if (v > m) { s = s * expf(m - v) + 1.f; m = v; }
        else s += expf(v - m);
    }
    __shared__ float sm[256], ss[256];
    sm[threadIdx.x] = m; ss[threadIdx.x] = s;
    __syncthreads();
    for (int off = 128; off > 0; off >>= 1) {
        if (threadIdx.x < off) {
            float m1 = sm[threadIdx.x], s1 = ss[threadIdx.x];
            float m2 = sm[threadIdx.x + off], s2 = ss[threadIdx.x + off];
            float M = fmaxf(m1, m2);
            sm[threadIdx.x] = M;
            ss[threadIdx.x] = s1 * expf(m1 - M) + s2 * expf(m2 - M);
        }
        __syncthreads();
    }
    if (threadIdx.x == 0) part[blockIdx.x] = make_float2(sm[0], ss[0]);
}

// in-block merge of the 64 (max,sum) partials -> (gmax, gsum), result in LDS slot 0
static __device__ __forceinline__ float2 merge_part(const float2* __restrict__ part, int t,
                                                    float* red2) {
    if (t < 64) {
        float2 p = part[t];
        float m = p.x, s = p.y;
        for (int off = 32; off > 0; off >>= 1) {
            float m2 = __shfl_xor(m, off);
            float s2 = __shfl_xor(s, off);
            float M = fmaxf(m, m2);
            s = s * expf(m - M) + s2 * expf(m2 - M);
            m = M;
        }
        if (t == 0) { red2[0] = m; red2[1] = s; }
    }
    __syncthreads();
    return make_float2(red2[0], red2[1]);
}

__global__ __launch_bounds__(256) void weighted_sum_kernel(const float* __restrict__ emb,
                                                           const float* __restrict__ logits,
                                                           const float2* __restrict__ part,
                                                           float* __restrict__ gpart, int n) {
    __shared__ float red2[2];
    float g = merge_part(part, threadIdx.x, red2).x;
    int wave = threadIdx.x >> 6;
    int lane = threadIdx.x & 63;
    int stride = gridDim.x * 4;
    float4 acc = make_float4(0.f, 0.f, 0.f, 0.f);
#pragma unroll 2
    for (int r = blockIdx.x * 4 + wave; r < n; r += stride) {
        float w = expf(logits[r] - g);
        float4 v = *(const float4*)(emb + (size_t)r * 256 + (lane << 2));
        acc.x += w * v.x; acc.y += w * v.y; acc.z += w * v.z; acc.w += w * v.w;
    }
    __shared__ float4 sm[256];
    sm[threadIdx.x] = acc;
    __syncthreads();
    if (wave == 0) {
        float4 a = sm[lane], b = sm[64 + lane], c = sm[128 + lane], d = sm[192 + lane];
        float4 s;
        s.x = (a.x + b.x) + (c.x + d.x);
        s.y = (a.y + b.y) + (c.y + d.y);
        s.z = (a.z + b.z) + (c.z + d.z);
        s.w = (a.w + b.w) + (c.w + d.w);
        *(float4*)(gpart + (size_t)blockIdx.x * 256 + (lane << 2)) = s;
    }
}

__global__ __launch_bounds__(256) void reduce_gpart_kernel(const float* __restrict__ gpart,
                                                           const float2* __restrict__ part,
                                                           float* __restrict__ outTail, int nb) {
    __shared__ float red2[2];
    float gsum = merge_part(part, threadIdx.x, red2).y;
    int rows = nb / gridDim.x;
    int r0 = blockIdx.x * rows;
    float s = 0.f;
    for (int r = r0; r < r0 + rows; ++r) s += gpart[(size_t)r * 256 + threadIdx.x];
    atomicAdd(&outTail[threadIdx.x], s / gsum);
}

// ---------------- launch ----------------

extern "C" void kernel_launch(void* const* d_in, const int* in_sizes, int n_in,
                              void* d_out, int out_size, void* d_ws, size_t ws_size,
                              hipStream_t stream) {
    const float* x  = (const float*)d_in[0];
    const int* ei   = (const int*)d_in[1];
    const float* W1 = (const float*)d_in[2];
    const float* b1 = (const float*)d_in[3];
    const float* W2 = (const float*)d_in[4];
    const float* b2 = (const float*)d_in[5];
    const float* Wa = (const float*)d_in[6];
    float* out = (float*)d_out;

    const int n = in_sizes[0] / 128;  // 50000
    const int E = in_sizes[1] / 2;    // 800000
    const int* srcA = ei;
    const int* dstA = ei + E;
    const int nb = (n + 1023) / 1024;
    const int WS_BLOCKS = 1024;

    // workspace layout (logits + degR adjacent -> single memset)
    unsigned short* xs16 = (unsigned short*)d_ws;         // n*128 fp16
    unsigned short* aggH = xs16 + (size_t)n * 128;        // n*128 bf16 (pre-swizzled)
    unsigned short* aggL = aggH + (size_t)n * 128;
    unsigned short* w1h  = aggL + (size_t)n * 128;        // 128*128 (pre-swizzled)
    unsigned short* w1l  = w1h + 128 * 128;
    unsigned short* w2h  = w1l + 128 * 128;               // 256*128 (pre-swizzled)
    unsigned short* w2l  = w2h + 256 * 128;
    float* dinv   = (float*)(w2l + 256 * 128);            // n
    float* logits = dinv + n;                             // n   (zeroed)
    int* degR     = (int*)(logits + n);                   // 8n  (zeroed, adjacent)
    int* rowptr   = degR + (size_t)8 * n;                 // n+1
    int* repOff   = rowptr + n + 1;                       // 8n
    int* partials = repOff + (size_t)8 * n;               // 64
    int* poff     = partials + 64;                        // 64
    float2* part  = (float2*)(poff + 64);                 // 64
    float* gpart  = (float*)(part + 64);                  // WS_BLOCKS*256
    int* epos     = (int*)(gpart + WS_BLOCKS * 256);      // E
    int* csrsrc   = epos + E;                             // E

    hipMemsetAsync(logits, 0, sizeof(float) * (size_t)(9 * n), stream);  // logits + degR
    hipMemsetAsync(out + (size_t)n * 256, 0, sizeof(float) * 256, stream);

    count_deg_kernel<<<(E + 255) / 256, 256, 0, stream>>>(dstA, E, n, degR, epos);
    scan_partial_kernel<<<nb, 256, 0, stream>>>(degR, n, partials);
    scan_offsets_kernel<<<1, 64, 0, stream>>>(partials, nb, poff, rowptr, n);
    scan_final_kernel<<<nb, 256, 0, stream>>>(degR, n, poff, rowptr);
    repsum_kernel<<<(n + 255) / 256, 256, 0, stream>>>(degR, rowptr, repOff, n);

    int scatterBlocks = (E + 255) / 256;
    int prescaleBlocks = (n + 3) / 4;
    int wconvBlocks = (128 * 128 + 256 * 128 + 255) / 256;
    prep_kernel<<<scatterBlocks + prescaleBlocks + wconvBlocks, 256, 0, stream>>>(
        srcA, dstA, epos, E, n, repOff, csrsrc, scatterBlocks,
        x, rowptr, dinv, (__half2*)xs16, prescaleBlocks,
        W1, W2, w1h, w1l, w2h, w2l);

    int aggBlocks = (n + 15) / 16;
    int gemmRows = (n + 127) / 128;

    aggregate_kernel<<<aggBlocks, 256, 0, stream>>>(xs16, dinv, rowptr, csrsrc, aggH, aggL, n);
    gemm_mfma<128, true, false, true><<<dim3(gemmRows, 1), 256, 0, stream>>>(
        aggH, aggL, w1h, w1l, b1, xs16, n, dinv, nullptr, nullptr);
    aggregate_kernel<<<aggBlocks, 256, 0, stream>>>(xs16, dinv, rowptr, csrsrc, aggH, aggL, n);
    gemm_mfma<256, false, true, false><<<dim3(gemmRows, 2), 256, 0, stream>>>(
        aggH, aggL, w2h, w2l, b2, out, n, nullptr, Wa, logits);

    maxsum_kernel<<<64, 256, 0, stream>>>(logits, n, part);
    weighted_sum_kernel<<<WS_BLOCKS, 256, 0, stream>>>(out, logits, part, gpart, n);
    reduce_gpart_kernel<<<32, 256, 0, stream>>>(gpart, part, out + (size_t)n * 256, WS_BLOCKS);
}

// Round 14
// 291.970 us; speedup vs baseline: 1.0182x; 1.0182x over previous
//
#include <hip/hip_runtime.h>
#include <hip/hip_fp16.h>
#include <math.h>

typedef __attribute__((ext_vector_type(8))) short bf16x8;
typedef __attribute__((ext_vector_type(4))) float f32x4;

static __device__ __forceinline__ unsigned short f2bf(float x) {
    unsigned u = __float_as_uint(x);
    unsigned r = (u + 0x7FFF + ((u >> 16) & 1)) >> 16;
    return (unsigned short)r;
}
static __device__ __forceinline__ float bf2f(unsigned short h) {
    return __uint_as_float(((unsigned)h) << 16);
}
static __device__ __forceinline__ void addh8(float a[8], uint4 v) {
    float2 f;
    f = __half22float2(*(const __half2*)&v.x); a[0] += f.x; a[1] += f.y;
    f = __half22float2(*(const __half2*)&v.y); a[2] += f.x; a[3] += f.y;
    f = __half22float2(*(const __half2*)&v.z); a[4] += f.x; a[5] += f.y;
    f = __half22float2(*(const __half2*)&v.w); a[6] += f.x; a[7] += f.y;
}
// async global->LDS 16B copy: LDS dest = wave-uniform base + lane*16
static __device__ __forceinline__ void gll16(const unsigned short* g, unsigned short* l) {
    __builtin_amdgcn_global_load_lds(
        (const __attribute__((address_space(1))) unsigned int*)(const void*)g,
        (__attribute__((address_space(3))) unsigned int*)(void*)l, 16, 0, 0);
}

// ---------------- CSR build ----------------

__global__ __launch_bounds__(256) void count_deg_kernel(const int* __restrict__ dst, int E,
                                                        int* __restrict__ deg,
                                                        int* __restrict__ epos) {
    int e = blockIdx.x * 256 + threadIdx.x;
    if (e < E) epos[e] = atomicAdd(&deg[dst[e]], 1);
}

__global__ __launch_bounds__(256) void scan_partial_kernel(const int* __restrict__ deg, int n,
                                                           int* __restrict__ partials) {
    int idx = blockIdx.x * 1024 + threadIdx.x * 4;
    int4 v = make_int4(0, 0, 0, 0);
    if (idx + 3 < n) v = *(const int4*)(deg + idx);
    else {
        if (idx < n) v.x = deg[idx];
        if (idx + 1 < n) v.y = deg[idx + 1];
        if (idx + 2 < n) v.z = deg[idx + 2];
    }
    int s = v.x + v.y + v.z + v.w;
    for (int off = 1; off < 64; off <<= 1) s += __shfl_xor(s, off);
    __shared__ int sm[4];
    int wave = threadIdx.x >> 6;
    if ((threadIdx.x & 63) == 0) sm[wave] = s;
    __syncthreads();
    if (threadIdx.x == 0) partials[blockIdx.x] = sm[0] + sm[1] + sm[2] + sm[3];
}

// scan_final with INLINE offsets scan (nb <= 64): each block wave-scans the
// partials itself -> no separate scan_offsets dispatch.
__global__ __launch_bounds__(256) void scan_final_kernel(const int* __restrict__ deg, int n,
                                                         const int* __restrict__ partials, int nbk,
                                                         int* __restrict__ rowptr) {
    int idx = blockIdx.x * 1024 + threadIdx.x * 4;
    int4 v = make_int4(0, 0, 0, 0);
    if (idx + 3 < n) v = *(const int4*)(deg + idx);
    else {
        if (idx < n) v.x = deg[idx];
        if (idx + 1 < n) v.y = deg[idx + 1];
        if (idx + 2 < n) v.z = deg[idx + 2];
    }
    int tsum = v.x + v.y + v.z + v.w;
    int lane = threadIdx.x & 63, wave = threadIdx.x >> 6;
    int s = tsum;
    for (int off = 1; off < 64; off <<= 1) {
        int u = __shfl_up(s, off);
        if (lane >= off) s += u;
    }
    __shared__ int wsum[4];
    __shared__ int bb;
    if (lane == 63) wsum[wave] = s;
    if (threadIdx.x < 64) {
        int pv = (threadIdx.x < nbk) ? partials[threadIdx.x] : 0;
        int ps = pv;
        for (int off = 1; off < 64; off <<= 1) {
            int u = __shfl_up(ps, off);
            if (threadIdx.x >= off) ps += u;
        }
        if (threadIdx.x == blockIdx.x) bb = ps - pv;       // exclusive prefix for this block
        if (blockIdx.x == 0 && threadIdx.x == 63) rowptr[n] = ps;  // grand total
    }
    __syncthreads();
    int base = bb;
    for (int w = 0; w < wave; ++w) base += wsum[w];
    int e0 = base + s - tsum;
    int4 o;
    o.x = e0; o.y = e0 + v.x; o.z = o.y + v.y; o.w = o.z + v.z;
    if (idx + 3 < n) *(int4*)(rowptr + idx) = o;
    else {
        if (idx < n) rowptr[idx] = o.x;
        if (idx + 1 < n) rowptr[idx + 1] = o.y;
        if (idx + 2 < n) rowptr[idx + 2] = o.z;
    }
}

// ---------------- fused prep: scatter | dinv+prescale | W convert (block-range dispatch) --------

__global__ __launch_bounds__(256) void prep_kernel(
    // scatter part
    const int* __restrict__ src, const int* __restrict__ dst, const int* __restrict__ epos, int E,
    const int* __restrict__ rowptr, int* __restrict__ csrsrc, int scatterBlocks,
    // prescale part
    const float* __restrict__ x, float* __restrict__ dinv,
    __half2* __restrict__ xs16, int n, int prescaleBlocks,
    // wconvert part
    const float* __restrict__ W1, const float* __restrict__ W2,
    unsigned short* __restrict__ w1h, unsigned short* __restrict__ w1l,
    unsigned short* __restrict__ w2h, unsigned short* __restrict__ w2l) {
    int b = blockIdx.x;
    if (b < scatterBlocks) {
        int e = b * 256 + threadIdx.x;
        if (e < E) csrsrc[rowptr[dst[e]] + epos[e]] = src[e];
    } else if (b < scatterBlocks + prescaleBlocks) {
        int node = (b - scatterBlocks) * 4 + (threadIdx.x >> 6);
        int lane = threadIdx.x & 63;
        if (node >= n) return;
        float di = rsqrtf((float)(rowptr[node + 1] - rowptr[node] + 1));
        if (lane == 0) dinv[node] = di;
        float2 v = *(const float2*)(x + (size_t)node * 128 + (lane << 1));
        xs16[(size_t)node * 64 + lane] = __floats2half2_rn(di * v.x, di * v.y);
    } else {
        int i = (b - scatterBlocks - prescaleBlocks) * 256 + threadIdx.x;
        if (i < 128 * 128) {
            int nn = i >> 7, k = i & 127;
            float v = W1[k * 128 + nn];
            unsigned short h = f2bf(v);
            int kp = (k & 64) + ((((k >> 3) & 7) ^ (nn & 7)) << 3) + (k & 7);
            w1h[nn * 128 + kp] = h;
            w1l[nn * 128 + kp] = f2bf(v - bf2f(h));
        } else if (i < 128 * 128 + 256 * 128) {
            int j = i - 128 * 128;
            int nn = j >> 7, k = j & 127;
            float v = W2[k * 256 + nn];
            unsigned short h = f2bf(v);
            int kp = (k & 64) + ((((k >> 3) & 7) ^ (nn & 7)) << 3) + (k & 7);
            w2h[nn * 128 + kp] = h;
            w2l[nn * 128 + kp] = f2bf(v - bf2f(h));
        }
    }
}

// ---------------- aggregation: fp16 gather (unroll 4), fp32 accum, pre-swizzled bf16 out ---------

__global__ __launch_bounds__(256) void aggregate_kernel(const unsigned short* __restrict__ X16,
                                                        const float* __restrict__ dinv,
                                                        const int* __restrict__ rowptr,
                                                        const int* __restrict__ csrsrc,
                                                        unsigned short* __restrict__ outH,
                                                        unsigned short* __restrict__ outL, int n) {
    int node = blockIdx.x * 16 + (threadIdx.x >> 4);
    int sl = threadIdx.x & 15;
    if (node >= n) return;
    const uint4* Xv = (const uint4*)X16;
    float acc[8] = {0.f, 0.f, 0.f, 0.f, 0.f, 0.f, 0.f, 0.f};
    addh8(acc, Xv[(size_t)node * 16 + sl]);
    int e0 = rowptr[node];
    int e1 = rowptr[node + 1];
    int e = e0;
    for (; e + 4 <= e1; e += 4) {
        int s0 = csrsrc[e], s1 = csrsrc[e + 1], s2 = csrsrc[e + 2], s3 = csrsrc[e + 3];
        uint4 v0 = Xv[(size_t)s0 * 16 + sl];
        uint4 v1 = Xv[(size_t)s1 * 16 + sl];
        uint4 v2 = Xv[(size_t)s2 * 16 + sl];
        uint4 v3 = Xv[(size_t)s3 * 16 + sl];
        addh8(acc, v0); addh8(acc, v1); addh8(acc, v2); addh8(acc, v3);
    }
    for (; e < e1; ++e) {
        uint4 v = Xv[(size_t)csrsrc[e] * 16 + sl];
        addh8(acc, v);
    }
    float di = dinv[node];
    unsigned short h[8], l[8];
#pragma unroll
    for (int j = 0; j < 8; ++j) {
        float f = di * acc[j];
        h[j] = f2bf(f);
        l[j] = f2bf(f - bf2f(h[j]));
    }
    uint4 hv, lv;
    hv.x = (unsigned)h[0] | ((unsigned)h[1] << 16);
    hv.y = (unsigned)h[2] | ((unsigned)h[3] << 16);
    hv.z = (unsigned)h[4] | ((unsigned)h[5] << 16);
    hv.w = (unsigned)h[6] | ((unsigned)h[7] << 16);
    lv.x = (unsigned)l[0] | ((unsigned)l[1] << 16);
    lv.y = (unsigned)l[2] | ((unsigned)l[3] << 16);
    lv.z = (unsigned)l[4] | ((unsigned)l[5] << 16);
    lv.w = (unsigned)l[6] | ((unsigned)l[7] << 16);
    int pos = ((sl & 8) | ((sl & 7) ^ (node & 7))) * 8;   // pre-swizzled granule slot
    *(uint4*)(outH + (size_t)node * 128 + pos) = hv;
    *(uint4*)(outL + (size_t)node * 128 + pos) = lv;
}

// ---------------- split-bf16 MFMA GEMM (BK=64 + global_load_lds, pre-swizzled global) ------------

template <int N, bool SCALE_DINV, bool DO_LOGITS, bool OUT_F16>
__global__ __launch_bounds__(256, 2) void gemm_mfma(const unsigned short* __restrict__ Ah,
                                                    const unsigned short* __restrict__ Al,
                                                    const unsigned short* __restrict__ Bth,
                                                    const unsigned short* __restrict__ Btl,
                                                    const float* __restrict__ bias,
                                                    void* __restrict__ Cout, int M,
                                                    const float* __restrict__ dinv,
                                                    const float* __restrict__ Wa,
                                                    float* __restrict__ logits) {
    __shared__ unsigned short AsH[128 * 64];
    __shared__ unsigned short AsL[128 * 64];
    __shared__ unsigned short BsH[128 * 64];
    __shared__ unsigned short BsL[128 * 64];

    const int t = threadIdx.x;
    const int lane = t & 63;
    const int wave = t >> 6;
    const int wrow = wave >> 1;
    const int wcol = wave & 1;
    const int lq = lane >> 4;
    const int lm = lane & 15;
    const int row0 = blockIdx.x * 128;
    const int col0 = blockIdx.y * 128;

    const int lr = lane >> 3;        // row within 8-row segment
    const int p8 = (lane & 7) * 8;   // granule offset in shorts (swizzle lives in global layout)

    f32x4 acc[4][4] = {};
    float lacc[4][4] = {};

    for (int kc = 0; kc < 2; ++kc) {
        __syncthreads();
#pragma unroll
        for (int j = 0; j < 4; ++j) {
            int seg = wave * 4 + j;                 // 0..15 (8 rows each)
            int r = seg * 8 + lr;
            size_t goA = (size_t)(row0 + r) * 128 + kc * 64 + p8;
            size_t goB = (size_t)(col0 + r) * 128 + kc * 64 + p8;
            gll16(Ah + goA, AsH + seg * 512);
            gll16(Al + goA, AsL + seg * 512);
            gll16(Bth + goB, BsH + seg * 512);
            gll16(Btl + goB, BsL + seg * 512);
        }
        __syncthreads();

#pragma unroll
        for (int ks = 0; ks < 2; ++ks) {
            bf16x8 ah[4], al[4], bh[4], bl[4];
            int gbase = ks * 4 + lq;
#pragma unroll
            for (int rt = 0; rt < 4; ++rt) {
                int ra = wrow * 64 + rt * 16 + lm;
                int off = ra * 64 + (gbase ^ (ra & 7)) * 8;
                ah[rt] = *(const bf16x8*)(AsH + off);
                al[rt] = *(const bf16x8*)(AsL + off);
            }
#pragma unroll
            for (int ct = 0; ct < 4; ++ct) {
                int nb = wcol * 64 + ct * 16 + lm;
                int off = nb * 64 + (gbase ^ (nb & 7)) * 8;
                bh[ct] = *(const bf16x8*)(BsH + off);
                bl[ct] = *(const bf16x8*)(BsL + off);
            }
#pragma unroll
            for (int rt = 0; rt < 4; ++rt)
#pragma unroll
                for (int ct = 0; ct < 4; ++ct) {
                    acc[rt][ct] = __builtin_amdgcn_mfma_f32_16x16x32_bf16(ah[rt], bh[ct], acc[rt][ct], 0, 0, 0);
                    acc[rt][ct] = __builtin_amdgcn_mfma_f32_16x16x32_bf16(al[rt], bh[ct], acc[rt][ct], 0, 0, 0);
                    acc[rt][ct] = __builtin_amdgcn_mfma_f32_16x16x32_bf16(ah[rt], bl[ct], acc[rt][ct], 0, 0, 0);
                }
        }
    }

    // epilogue: C/D frag layout col = lm, row = lq*4 + reg
#pragma unroll
    for (int ct = 0; ct < 4; ++ct) {
        int col = col0 + wcol * 64 + ct * 16 + lm;
        float bc = bias[col];
        float wac = DO_LOGITS ? Wa[col] : 0.f;
#pragma unroll
        for (int rt = 0; rt < 4; ++rt) {
            int rowb = row0 + wrow * 64 + rt * 16 + lq * 4;
#pragma unroll
            for (int reg = 0; reg < 4; ++reg) {
                int gr = rowb + reg;
                if (gr < M) {
                    float o = fmaxf(acc[rt][ct][reg] + bc, 0.f);
                    if (SCALE_DINV) o *= dinv[gr];
                    if (OUT_F16) ((__half*)Cout)[(size_t)gr * N + col] = __float2half(o);
                    else ((float*)Cout)[(size_t)gr * N + col] = o;
                    if (DO_LOGITS) lacc[rt][reg] += o * wac;
                }
            }
        }
    }

    if (DO_LOGITS) {
#pragma unroll
        for (int rt = 0; rt < 4; ++rt)
#pragma unroll
            for (int reg = 0; reg < 4; ++reg) {
                float s = lacc[rt][reg];
                s += __shfl_xor(s, 1);
                s += __shfl_xor(s, 2);
                s += __shfl_xor(s, 4);
                s += __shfl_xor(s, 8);
                int gr = row0 + wrow * 64 + rt * 16 + lq * 4 + reg;
                if (lm == 0 && gr < M) atomicAdd(&logits[gr], s);
            }
    }
}

// ---------------- attention pooling ----------------

// also zeroes the graph-embedding tail (block 0) -> removes a memset dispatch
__global__ __launch_bounds__(256) void maxsum_kernel(const float* __restrict__ logits, int n,
                                                     float2* __restrict__ part,
                                                     float* __restrict__ outTail) {
    if (blockIdx.x == 0) outTail[threadIdx.x] = 0.f;
    float m = -INFINITY, s = 0.f;
    for (int i = blockIdx.x * 256 + threadIdx.x; i < n; i += gridDim.x * 256) {
        float v = logits[i];
        if (v > m) { s = s * expf(m - v) + 1.f; m = v; }
        else s += expf(v - m);
    }
    __shared__ float sm[256], ss[256];
    sm[threadIdx.x] = m; ss[threadIdx.x] = s;
    __syncthreads();
    for (int off = 128; off > 0; off >>= 1) {
        if (threadIdx.x < off) {
            float m1 = sm[threadIdx.x], s1 = ss[threadIdx.x];
            float m2 = sm[threadIdx.x + off], s2 = ss[threadIdx.x + off];
            float M = fmaxf(m1, m2);
            sm[threadIdx.x] = M;
            ss[threadIdx.x] = s1 * expf(m1 - M) + s2 * expf(m2 - M);
        }
        __syncthreads();
    }
    if (threadIdx.x == 0) part[blockIdx.x] = make_float2(sm[0], ss[0]);
}

// in-block merge of the 64 (max,sum) partials -> (gmax, gsum), result in LDS slot 0
static __device__ __forceinline__ float2 merge_part(const float2* __restrict__ part, int t,
                                                    float* red2) {
    if (t < 64) {
        float2 p = part[t];
        float m = p.x, s = p.y;
        for (int off = 32; off > 0; off >>= 1) {
            float m2 = __shfl_xor(m, off);
            float s2 = __shfl_xor(s, off);
            float M = fmaxf(m, m2);
            s = s * expf(m - M) + s2 * expf(m2 - M);
            m = M;
        }
        if (t == 0) { red2[0] = m; red2[1] = s; }
    }
    __syncthreads();
    return make_float2(red2[0], red2[1]);
}

__global__ __launch_bounds__(256) void weighted_sum_kernel(const float* __restrict__ emb,
                                                           const float* __restrict__ logits,
                                                           const float2* __restrict__ part,
                                                           float* __restrict__ gpart, int n) {
    __shared__ float red2[2];
    float g = merge_part(part, threadIdx.x, red2).x;
    int wave = threadIdx.x >> 6;
    int lane = threadIdx.x & 63;
    int stride = gridDim.x * 4;
    float4 acc = make_float4(0.f, 0.f, 0.f, 0.f);
#pragma unroll 2
    for (int r = blockIdx.x * 4 + wave; r < n; r += stride) {
        float w = expf(logits[r] - g);
        float4 v = *(const float4*)(emb + (size_t)r * 256 + (lane << 2));
        acc.x += w * v.x; acc.y += w * v.y; acc.z += w * v.z; acc.w += w * v.w;
    }
    __shared__ float4 sm[256];
    sm[threadIdx.x] = acc;
    __syncthreads();
    if (wave == 0) {
        float4 a = sm[lane], b = sm[64 + lane], c = sm[128 + lane], d = sm[192 + lane];
        float4 s;
        s.x = (a.x + b.x) + (c.x + d.x);
        s.y = (a.y + b.y) + (c.y + d.y);
        s.z = (a.z + b.z) + (c.z + d.z);
        s.w = (a.w + b.w) + (c.w + d.w);
        *(float4*)(gpart + (size_t)blockIdx.x * 256 + (lane << 2)) = s;
    }
}

__global__ __launch_bounds__(256) void reduce_gpart_kernel(const float* __restrict__ gpart,
                                                           const float2* __restrict__ part,
                                                           float* __restrict__ outTail, int nb) {
    __shared__ float red2[2];
    float gsum = merge_part(part, threadIdx.x, red2).y;
    int rows = nb / gridDim.x;
    int r0 = blockIdx.x * rows;
    float s = 0.f;
    for (int r = r0; r < r0 + rows; ++r) s += gpart[(size_t)r * 256 + threadIdx.x];
    atomicAdd(&outTail[threadIdx.x], s / gsum);
}

// ---------------- launch ----------------

extern "C" void kernel_launch(void* const* d_in, const int* in_sizes, int n_in,
                              void* d_out, int out_size, void* d_ws, size_t ws_size,
                              hipStream_t stream) {
    const float* x  = (const float*)d_in[0];
    const int* ei   = (const int*)d_in[1];
    const float* W1 = (const float*)d_in[2];
    const float* b1 = (const float*)d_in[3];
    const float* W2 = (const float*)d_in[4];
    const float* b2 = (const float*)d_in[5];
    const float* Wa = (const float*)d_in[6];
    float* out = (float*)d_out;

    const int n = in_sizes[0] / 128;  // 50000
    const int E = in_sizes[1] / 2;    // 800000
    const int* srcA = ei;
    const int* dstA = ei + E;
    const int nb = (n + 1023) / 1024;
    const int WS_BLOCKS = 1024;

    // workspace layout (logits and deg adjacent -> single memset)
    unsigned short* xs16 = (unsigned short*)d_ws;         // n*128 fp16
    unsigned short* aggH = xs16 + (size_t)n * 128;        // n*128 bf16 (pre-swizzled)
    unsigned short* aggL = aggH + (size_t)n * 128;
    unsigned short* w1h  = aggL + (size_t)n * 128;        // 128*128 (pre-swizzled)
    unsigned short* w1l  = w1h + 128 * 128;
    unsigned short* w2h  = w1l + 128 * 128;               // 256*128 (pre-swizzled)
    unsigned short* w2l  = w2h + 256 * 128;
    float* dinv   = (float*)(w2l + 256 * 128);            // n
    float* logits = dinv + n;                             // n   (zeroed)
    int* deg      = (int*)(logits + n);                   // n   (zeroed, adjacent)
    int* rowptr   = deg + n;                              // n+1
    int* partials = rowptr + n + 1;                       // 64
    float2* part  = (float2*)(partials + 64);             // 64
    float* gpart  = (float*)(part + 64);                  // WS_BLOCKS*256
    int* epos     = (int*)(gpart + WS_BLOCKS * 256);      // E
    int* csrsrc   = epos + E;                             // E

    hipMemsetAsync(logits, 0, sizeof(float) * (size_t)(2 * n), stream);  // logits + deg

    count_deg_kernel<<<(E + 255) / 256, 256, 0, stream>>>(dstA, E, deg, epos);
    scan_partial_kernel<<<nb, 256, 0, stream>>>(deg, n, partials);
    scan_final_kernel<<<nb, 256, 0, stream>>>(deg, n, partials, nb, rowptr);

    int scatterBlocks = (E + 255) / 256;
    int prescaleBlocks = (n + 3) / 4;
    int wconvBlocks = (128 * 128 + 256 * 128 + 255) / 256;
    prep_kernel<<<scatterBlocks + prescaleBlocks + wconvBlocks, 256, 0, stream>>>(
        srcA, dstA, epos, E, rowptr, csrsrc, scatterBlocks,
        x, dinv, (__half2*)xs16, n, prescaleBlocks,
        W1, W2, w1h, w1l, w2h, w2l);

    int aggBlocks = (n + 15) / 16;
    int gemmRows = (n + 127) / 128;

    aggregate_kernel<<<aggBlocks, 256, 0, stream>>>(xs16, dinv, rowptr, csrsrc, aggH, aggL, n);
    gemm_mfma<128, true, false, true><<<dim3(gemmRows, 1), 256, 0, stream>>>(
        aggH, aggL, w1h, w1l, b1, xs16, n, dinv, nullptr, nullptr);
    aggregate_kernel<<<aggBlocks, 256, 0, stream>>>(xs16, dinv, rowptr, csrsrc, aggH, aggL, n);
    gemm_mfma<256, false, true, false><<<dim3(gemmRows, 2), 256, 0, stream>>>(
        aggH, aggL, w2h, w2l, b2, out, n, nullptr, Wa, logits);

    maxsum_kernel<<<64, 256, 0, stream>>>(logits, n, part, out + (size_t)n * 256);
    weighted_sum_kernel<<<WS_BLOCKS, 256, 0, stream>>>(out, logits, part, gpart, n);
    reduce_gpart_kernel<<<32, 256, 0, stream>>>(gpart, part, out + (size_t)n * 256, WS_BLOCKS);
}